// Round 12
// baseline (156.260 us; speedup 1.0000x reference)
//
#include <hip/hip_runtime.h>
#include <hip/hip_bf16.h>
#include <cstdint>

#define D_MODEL 1024
#define SEQ     2048
#define SCALE   0.125f
#define P_ELEMS 2228224   // per-batch packed triangular elems: 16384*136

typedef __attribute__((ext_vector_type(8))) _Float16 f16x8;
typedef __attribute__((ext_vector_type(8))) unsigned short u16x8;
typedef __attribute__((ext_vector_type(4))) float f32x4;

__device__ __forceinline__ unsigned short f2h(float f) {
  _Float16 h = (_Float16)f;
  return __builtin_bit_cast(unsigned short, h);
}
__device__ __forceinline__ float h2f(unsigned short u) {
  return (float)__builtin_bit_cast(_Float16, u);
}

__device__ __forceinline__ void gll16(const void* g, void* lds_p) {
  __builtin_amdgcn_global_load_lds(
      (const __attribute__((address_space(1))) unsigned int*)(uintptr_t)g,
      (__attribute__((address_space(3))) unsigned int*)(unsigned int)(uintptr_t)lds_p,
      16, 0, 0);
}

#define WAITV8 asm volatile("s_waitcnt vmcnt(8)" ::: "memory")
#define WAITV4 asm volatile("s_waitcnt vmcnt(4)" ::: "memory")
#define WAITV0 asm volatile("s_waitcnt vmcnt(0)" ::: "memory")
#define WAITL8 asm volatile("s_waitcnt lgkmcnt(8)" ::: "memory")
#define WAITL0 asm volatile("s_waitcnt lgkmcnt(0)" ::: "memory")
#define SCHEDB __builtin_amdgcn_sched_barrier(0)
#define BAR    __builtin_amdgcn_s_barrier()
#define PRIO1  __builtin_amdgcn_s_setprio(1)
#define PRIO0  __builtin_amdgcn_s_setprio(0)
#define MFMA16(a, b, c) __builtin_amdgcn_mfma_f32_16x16x32_f16(a, b, c, 0, 0, 0)

// ============ 128-tile pipeline (4 waves) — V projection, qk_scores, pv ============
__device__ __forceinline__ void stage_tile(const unsigned short* gA, const unsigned short* gB,
                                           size_t sA, size_t sB,
                                           int k0, unsigned short* buf, int w, int lane) {
  int rl = lane >> 3;
  int sg = ((lane & 7) ^ rl) << 3;
#pragma unroll
  for (int j = 0; j < 4; j++) {
    int c = w * 4 + j;
    int row = c * 8 + rl;
    gll16(gA + (size_t)row * sA + k0 + sg, buf + c * 512);
    gll16(gB + (size_t)row * sB + k0 + sg, buf + 8192 + c * 512);
  }
}

__device__ __forceinline__ void gemm_core(const unsigned short* gA, const unsigned short* gB,
                                          size_t sA, size_t sB,
                                          unsigned short* lds0, unsigned short* lds1, int nt,
                                          int w, int lane, int wr, int wc, int l15, int l4,
                                          f32x4 acc[4][4]) {
  stage_tile(gA, gB, sA, sB, 0, lds0, w, lane);
  stage_tile(gA, gB, sA, sB, 64, lds1, w, lane);
  WAITV8; SCHEDB; BAR;
  for (int t = 0; t < nt; t++) {
    const unsigned short* buf = (t & 1) ? lds1 : lds0;
    const unsigned short* bA = buf;
    const unsigned short* bB = buf + 8192;
    f16x8 a0[4], b0[4], a1[4], b1[4];
#pragma unroll
    for (int m = 0; m < 4; m++) {
      int row = wr * 64 + m * 16 + l15, rs = row & 7;
      a0[m] = *(const f16x8*)(bA + row * 64 + ((l4 ^ rs) << 3));
    }
#pragma unroll
    for (int n = 0; n < 4; n++) {
      int row = wc * 64 + n * 16 + l15, rs = row & 7;
      b0[n] = *(const f16x8*)(bB + row * 64 + ((l4 ^ rs) << 3));
    }
#pragma unroll
    for (int m = 0; m < 4; m++) {
      int row = wr * 64 + m * 16 + l15, rs = row & 7;
      a1[m] = *(const f16x8*)(bA + row * 64 + (((4 + l4) ^ rs) << 3));
    }
#pragma unroll
    for (int n = 0; n < 4; n++) {
      int row = wc * 64 + n * 16 + l15, rs = row & 7;
      b1[n] = *(const f16x8*)(bB + row * 64 + (((4 + l4) ^ rs) << 3));
    }
    WAITL8; SCHEDB;
    PRIO1;
#pragma unroll
    for (int m = 0; m < 4; m++)
#pragma unroll
      for (int n = 0; n < 4; n++)
        acc[m][n] = MFMA16(a0[m], b0[n], acc[m][n]);
    PRIO0;
    WAITL0; SCHEDB; BAR;
    if (t + 2 < nt) stage_tile(gA, gB, sA, sB, (t + 2) * 64,
                               (unsigned short*)buf, w, lane);
    PRIO1;
#pragma unroll
    for (int m = 0; m < 4; m++)
#pragma unroll
      for (int n = 0; n < 4; n++)
        acc[m][n] = MFMA16(a1[m], b1[n], acc[m][n]);
    PRIO0;
    if (t + 2 < nt) { WAITV8; } else { WAITV0; }
    SCHEDB; BAR;
  }
}

// ============ 8-phase 256x256 pipeline (8 waves) — Q,K projections ============
// Stage one quarter (128 rows x 64 cols f16, 2 gll/thread), source-pre-swizzled.
__device__ __forceinline__ void stage_q(const unsigned short* g, int k0,
                                        unsigned short* dst, int w, int lane) {
  int rl = lane >> 3;
  int sg = ((lane & 7) ^ rl) << 3;
#pragma unroll
  for (int j = 0; j < 2; j++) {
    int c = w * 2 + j;              // 0..15
    int row = c * 8 + rl;           // 0..127
    gll16(g + (size_t)row * 1024 + k0 + sg, dst + c * 512);
  }
}

// ---- kernel: QK GEMM, 256x256 tile, 8 waves, 8-phase counted-vmcnt ----
__global__ __launch_bounds__(512, 2) void qkv8(const unsigned short* __restrict__ xb,
                                               const unsigned short* __restrict__ wt,
                                               const float* __restrict__ b0f,
                                               const float* __restrict__ b1f,
                                               unsigned short* __restrict__ Qp,
                                               unsigned short* __restrict__ Kp) {
  __shared__ unsigned short lds[2][32768];  // [buf][A-low|A-high|B-low|B-high] 8192 each
  int m0 = blockIdx.x * 256;
  int n0 = blockIdx.y * 256;                // 0..1792
  int z = n0 >> 10, nz = n0 & 1023;
  const unsigned short* gA = xb + (size_t)m0 * 1024;
  const unsigned short* gB = wt + (size_t)z * 1048576 + (size_t)nz * 1024;
  const float* bias = z ? b1f : b0f;
  unsigned short* O = z ? Kp : Qp;
  int tid = threadIdx.x, lane = tid & 63, w = tid >> 6;
  int wr = w >> 2, wc = w & 3, l15 = lane & 15, l4 = lane >> 4;
  f32x4 acc[8][4] = {};

  // prologue: t0 fully, t1 A-quarters
  stage_q(gA,          0, &lds[0][0],     w, lane);
  stage_q(gA + 131072, 0, &lds[0][8192],  w, lane);
  stage_q(gB,          0, &lds[0][16384], w, lane);
  stage_q(gB + 131072, 0, &lds[0][24576], w, lane);
  stage_q(gA,          64, &lds[1][0],    w, lane);
  stage_q(gA + 131072, 64, &lds[1][8192], w, lane);
  WAITV4; SCHEDB; BAR;

  f16x8 a0[4], a1[4], a2[4], a3[4], b0v[4], b1v[4];
  for (int t = 0; t < 16; t++) {
    unsigned short* buf = &lds[t & 1][0];
    unsigned short* oth = &lds[(t & 1) ^ 1][0];
    int kc1 = (t + 1) * 64, kc2 = (t + 2) * 64;
    // ---- Ph1: read a(m0-3,k0)+b(k0); stage B-low(t+1); MFMA m0-3 x k0
#pragma unroll
    for (int m = 0; m < 4; m++) {
      int row = wr * 128 + m * 16 + l15, rs = row & 7;
      a0[m] = *(const f16x8*)(buf + row * 64 + ((l4 ^ rs) << 3));
    }
#pragma unroll
    for (int n = 0; n < 4; n++) {
      int row = wc * 64 + n * 16 + l15, rs = row & 7;
      b0v[n] = *(const f16x8*)(buf + 16384 + row * 64 + ((l4 ^ rs) << 3));
    }
    if (t + 1 < 16) stage_q(gB, kc1, oth + 16384, w, lane);
    BAR; WAITL0; SCHEDB;
    PRIO1;
#pragma unroll
    for (int m = 0; m < 4; m++)
#pragma unroll
      for (int n = 0; n < 4; n++)
        acc[m][n] = MFMA16(a0[m], b0v[n], acc[m][n]);
    PRIO0;
    BAR;
    // ---- Ph2: read a(m4-7,k0)+a(m0-3,k1); stage B-high(t+1); MFMA m4-7 x k0
#pragma unroll
    for (int m = 0; m < 4; m++) {
      int row = wr * 128 + 64 + m * 16 + l15, rs = row & 7;
      a1[m] = *(const f16x8*)(buf + row * 64 + ((l4 ^ rs) << 3));
    }
#pragma unroll
    for (int m = 0; m < 4; m++) {
      int row = wr * 128 + m * 16 + l15, rs = row & 7;
      a2[m] = *(const f16x8*)(buf + row * 64 + (((4 + l4) ^ rs) << 3));
    }
    if (t + 1 < 16) stage_q(gB + 131072, kc1, oth + 24576, w, lane);
    BAR; WAITL0; SCHEDB;
    PRIO1;
#pragma unroll
    for (int m = 0; m < 4; m++)
#pragma unroll
      for (int n = 0; n < 4; n++)
        acc[m + 4][n] = MFMA16(a1[m], b0v[n], acc[m + 4][n]);
    PRIO0;
    BAR;
    // ---- Ph3: read a(m4-7,k1)+b(k1); MFMA m0-3 x k1
#pragma unroll
    for (int m = 0; m < 4; m++) {
      int row = wr * 128 + 64 + m * 16 + l15, rs = row & 7;
      a3[m] = *(const f16x8*)(buf + row * 64 + (((4 + l4) ^ rs) << 3));
    }
#pragma unroll
    for (int n = 0; n < 4; n++) {
      int row = wc * 64 + n * 16 + l15, rs = row & 7;
      b1v[n] = *(const f16x8*)(buf + 16384 + row * 64 + (((4 + l4) ^ rs) << 3));
    }
    BAR; WAITL0; SCHEDB;
    PRIO1;
#pragma unroll
    for (int m = 0; m < 4; m++)
#pragma unroll
      for (int n = 0; n < 4; n++)
        acc[m][n] = MFMA16(a2[m], b1v[n], acc[m][n]);
    PRIO0;
    BAR;
    // ---- Ph4: stage A-low+A-high(t+2) into just-freed buf; MFMA m4-7 x k1
    if (t + 2 < 16) {
      stage_q(gA, kc2, buf, w, lane);
      stage_q(gA + 131072, kc2, buf + 8192, w, lane);
    }
    PRIO1;
#pragma unroll
    for (int m = 0; m < 4; m++)
#pragma unroll
      for (int n = 0; n < 4; n++)
        acc[m + 4][n] = MFMA16(a3[m], b1v[n], acc[m + 4][n]);
    PRIO0;
    if (t + 1 < 16) { if (t + 2 < 16) { WAITV4; } else { WAITV0; } }
    SCHEDB; BAR;
  }

  // epilogue: bias + f16 store
#pragma unroll
  for (int m = 0; m < 8; m++)
#pragma unroll
    for (int n = 0; n < 4; n++) {
      int cl = wc * 64 + n * 16 + l15;
      float bv = bias[nz + cl];
#pragma unroll
      for (int r = 0; r < 4; r++) {
        int row = m0 + wr * 128 + m * 16 + l4 * 4 + r;
        O[(size_t)row * 1024 + nz + cl] = f2h(acc[m][n][r] + bv);
      }
    }
}

// ---- kernel 1: fused converts. blocks 0..4095: x f32->f16; 4096..7167: W transpose ----
__global__ __launch_bounds__(256) void cvt_fused(const float* __restrict__ x,
                                                 const float* __restrict__ W0,
                                                 const float* __restrict__ W1,
                                                 const float* __restrict__ W2,
                                                 unsigned short* __restrict__ xb,
                                                 unsigned short* __restrict__ wt) {
  __shared__ float t[32][33];
  int bid = blockIdx.x;
  int tid = threadIdx.x;
  if (bid < 4096) {
    int i = bid * 256 + tid;
    const float4* p = (const float4*)x + (size_t)i * 2;
    float4 a = p[0], b = p[1];
    u16x8 r;
    r[0] = f2h(a.x); r[1] = f2h(a.y); r[2] = f2h(a.z); r[3] = f2h(a.w);
    r[4] = f2h(b.x); r[5] = f2h(b.y); r[6] = f2h(b.z); r[7] = f2h(b.w);
    *((u16x8*)xb + i) = r;
  } else {
    int id = bid - 4096;              // 0..3071
    int z = id >> 10, rem = id & 1023;
    int bx = rem & 31, by = rem >> 5;
    const float* W = (z == 0) ? W0 : (z == 1 ? W1 : W2);
    unsigned short* o = wt + (size_t)z * 1048576;
    int c0 = bx * 32, r0 = by * 32;
    int tx = tid & 31, ty = tid >> 5;
    for (int i = 0; i < 4; i++)
      t[ty + 8 * i][tx] = W[(size_t)(r0 + ty + 8 * i) * 1024 + c0 + tx];
    __syncthreads();
    for (int i = 0; i < 4; i++)
      o[(size_t)(c0 + ty + 8 * i) * 1024 + r0 + tx] = f2h(t[tx][ty + 8 * i]);
  }
}

// ---- kernel: V projection (128-tile core), n_off selects column range ----
__global__ __launch_bounds__(256) void qkv_gemm(const unsigned short* __restrict__ xb,
                                                const unsigned short* __restrict__ wt,
                                                const float* __restrict__ b0,
                                                const float* __restrict__ b1,
                                                const float* __restrict__ b2,
                                                unsigned short* __restrict__ Qp,
                                                unsigned short* __restrict__ Kp,
                                                unsigned short* __restrict__ vtp,
                                                int n_off) {
  __shared__ unsigned short lds[2][16384];   // [buf][A 8192 | B 8192]
  int m0 = blockIdx.x * 128;
  int n0 = n_off + blockIdx.y * 128;
  int z = n0 >> 10, nz = n0 & 1023;
  const unsigned short* gA = xb + (size_t)m0 * 1024;
  const unsigned short* gB = wt + (size_t)z * 1048576 + (size_t)nz * 1024;
  const float* bias = (z == 0) ? b0 : (z == 1 ? b1 : b2);
  int tid = threadIdx.x, lane = tid & 63, w = tid >> 6;
  int wr = w >> 1, wc = w & 1, l15 = lane & 15, l4 = lane >> 4;
  f32x4 acc[4][4] = {};
  gemm_core(gA, gB, 1024, 1024, &lds[0][0], &lds[1][0], 16, w, lane, wr, wc, l15, l4, acc);

  if (z < 2) {
    unsigned short* O = (z == 0) ? Qp : Kp;
#pragma unroll
    for (int m = 0; m < 4; m++)
#pragma unroll
      for (int n = 0; n < 4; n++) {
        int cl = wc * 64 + n * 16 + l15;
        float bv = bias[nz + cl];
#pragma unroll
        for (int r = 0; r < 4; r++) {
          int row = m0 + wr * 64 + m * 16 + l4 * 4 + r;
          O[(size_t)row * 1024 + nz + cl] = f2h(acc[m][n][r] + bv);
        }
      }
  } else {
    // V: transpose 128x128 tile in LDS, then coalesced store to vtp[b][d][s]
    unsigned short* T = &lds[0][0];          // 128 x 136 f16
#pragma unroll
    for (int m = 0; m < 4; m++)
#pragma unroll
      for (int n = 0; n < 4; n++) {
        int cl = wc * 64 + n * 16 + l15;     // d-local
        float bv = bias[nz + cl];
#pragma unroll
        for (int r = 0; r < 4; r++) {
          int rl = wr * 64 + m * 16 + l4 * 4 + r;   // s-local
          T[cl * 136 + rl] = f2h(acc[m][n][r] + bv);
        }
      }
    __syncthreads();
    int bidx = m0 >> 11, s0 = m0 & 2047;
#pragma unroll
    for (int i = 0; i < 8; i++) {
      int d = w * 32 + i * 4 + (lane >> 4);
      int ch = lane & 15;
      u16x8 v = *(const u16x8*)(T + d * 136 + ch * 8);
      *(u16x8*)(vtp + ((size_t)bidx * 1024 + nz + d) * 2048 + s0 + ch * 8) = v;
    }
  }
}

// ---- kernel: scores = Q K^T * SCALE, causal mask, triangular-packed f16 ----
__global__ __launch_bounds__(256) void qk_scores(const unsigned short* __restrict__ Q,
                                                 const unsigned short* __restrict__ Kb,
                                                 unsigned short* __restrict__ sc) {
  __shared__ unsigned short lds[2][16384];
  int b = blockIdx.y;
  int i = blockIdx.x;
  int qt = (int)((sqrtf(8.f * i + 1.f) - 1.f) * 0.5f);
  while ((qt + 1) * (qt + 2) / 2 <= i) qt++;
  while (qt * (qt + 1) / 2 > i) qt--;
  int kt = i - qt * (qt + 1) / 2;
  int Wspan = (qt + 1) << 7;
  const unsigned short* gA = Q  + ((size_t)b * 2048 + qt * 128) * 1024;
  const unsigned short* gB = Kb + ((size_t)b * 2048 + kt * 128) * 1024;
  unsigned short* outp = sc + (size_t)b * P_ELEMS + (size_t)16384 * (qt * (qt + 1) / 2);
  int tid = threadIdx.x, lane = tid & 63, w = tid >> 6;
  int wr = w >> 1, wc = w & 1, l15 = lane & 15, l4 = lane >> 4;
  f32x4 acc[4][4] = {};
  gemm_core(gA, gB, 1024, 1024, &lds[0][0], &lds[1][0], 16, w, lane, wr, wc, l15, l4, acc);
#pragma unroll
  for (int m = 0; m < 4; m++)
#pragma unroll
    for (int n = 0; n < 4; n++) {
      int cl = wc * 64 + n * 16 + l15;
      int kv = kt * 128 + cl;
#pragma unroll
      for (int r = 0; r < 4; r++) {
        int rl = wr * 64 + m * 16 + l4 * 4 + r;
        int srow = qt * 128 + rl;
        float v = acc[m][n][r] * SCALE;
        if (kv > srow) v = -30000.f;
        outp[(size_t)rl * Wspan + kv] = f2h(v);
      }
    }
}

// ---- kernel: row softmax over f16 scores, write f16 P ----
__global__ __launch_bounds__(256) void softmax_row(const unsigned short* __restrict__ sc,
                                                   unsigned short* __restrict__ pb) {
  __shared__ float redm[4];
  __shared__ float reds[4];
  int srow = blockIdx.x;
  int b = srow >> 11, sl = srow & 2047;
  int qt = sl >> 7;
  int Wspan = (qt + 1) << 7;
  size_t rb = (size_t)b * P_ELEMS + (size_t)16384 * (qt * (qt + 1) / 2) + (size_t)(sl & 127) * Wspan;
  const u16x8* src = (const u16x8*)(sc + rb);
  int nv = Wspan >> 3;
  int t = threadIdx.x, lane = t & 63, w = t >> 6;
  bool h0 = t < nv;
  float v[8];
  float mx = -1e30f;
  if (h0) {
    u16x8 raw = src[t];
#pragma unroll
    for (int j = 0; j < 8; j++) { v[j] = h2f(raw[j]); mx = fmaxf(mx, v[j]); }
  }
  for (int off = 1; off < 64; off <<= 1) mx = fmaxf(mx, __shfl_xor(mx, off, 64));
  if (lane == 0) redm[w] = mx;
  __syncthreads();
  mx = fmaxf(fmaxf(redm[0], redm[1]), fmaxf(redm[2], redm[3]));
  float s = 0.f;
  if (h0) {
#pragma unroll
    for (int j = 0; j < 8; j++) { v[j] = __expf(v[j] - mx); s += v[j]; }
  }
  for (int off = 1; off < 64; off <<= 1) s += __shfl_xor(s, off, 64);
  if (lane == 0) reds[w] = s;
  __syncthreads();
  s = reds[0] + reds[1] + reds[2] + reds[3];
  float inv = 1.f / s;
  if (h0) {
    u16x8 o;
#pragma unroll
    for (int j = 0; j < 8; j++) o[j] = f2h(v[j] * inv);
    *((u16x8*)(pb + rb) + t) = o;
  }
}

// ---- kernel: O = P Vt — paired tiles (qt=p and 15-p): 34 K-iters per block ----
__global__ __launch_bounds__(256) void pv_gemm(const unsigned short* __restrict__ pb,
                                               const unsigned short* __restrict__ vtp,
                                               float* __restrict__ outp) {
  __shared__ unsigned short lds[2][16384];
  int p = blockIdx.x;
  int n0 = blockIdx.y * 128;
  int b = blockIdx.z;
  int tid = threadIdx.x, lane = tid & 63, w = tid >> 6;
  int wr = w >> 1, wc = w & 1, l15 = lane & 15, l4 = lane >> 4;
  const unsigned short* gB = vtp + (size_t)b * 1024 * 2048 + (size_t)n0 * 2048;
#pragma unroll
  for (int which = 0; which < 2; which++) {
    int qt = which ? (15 - p) : p;
    int Wspan = (qt + 1) << 7;
    const unsigned short* gA = pb + (size_t)b * P_ELEMS + (size_t)16384 * (qt * (qt + 1) / 2);
    float* O = outp + ((size_t)b * 2048 + qt * 128) * 1024;
    f32x4 acc[4][4] = {};
    gemm_core(gA, gB, Wspan, 2048, &lds[0][0], &lds[1][0], 2 * (qt + 1),
              w, lane, wr, wc, l15, l4, acc);
#pragma unroll
    for (int m = 0; m < 4; m++)
#pragma unroll
      for (int n = 0; n < 4; n++) {
        int cl = n0 + wc * 64 + n * 16 + l15;
#pragma unroll
        for (int r = 0; r < 4; r++) {
          int rl = wr * 64 + m * 16 + l4 * 4 + r;
          O[(size_t)rl * 1024 + cl] = acc[m][n][r];
        }
      }
  }
}

extern "C" void kernel_launch(void* const* d_in, const int* in_sizes, int n_in,
                              void* d_out, int out_size, void* d_ws, size_t ws_size,
                              hipStream_t stream) {
  const float* x  = (const float*)d_in[0];
  const float* Wq = (const float*)d_in[1];
  const float* bq = (const float*)d_in[2];
  const float* Wk = (const float*)d_in[3];
  const float* bk = (const float*)d_in[4];
  const float* Wv = (const float*)d_in[5];
  const float* bv = (const float*)d_in[6];
  float* out = (float*)d_out;

  unsigned short* ws  = (unsigned short*)d_ws;
  unsigned short* wt  = ws;                          // 3,145,728 ushorts
  unsigned short* Qp  = ws + 3145728;                // 8,388,608
  unsigned short* Kp  = ws + 11534336;               // 8,388,608
  unsigned short* vtp = ws + 19922944;               // 8,388,608 (V^T [b][d][s])
  unsigned short* sc  = ws + 28311552;               // 4*P_ELEMS f16 scores
  unsigned short* pb  = ws + 37224448;               // 4*P_ELEMS f16 P
  unsigned short* xb  = (unsigned short*)d_out;      // x f16 scratch (overwritten by pv)

  cvt_fused<<<7168, 256, 0, stream>>>(x, Wq, Wk, Wv, xb, wt);
  qkv8<<<dim3(32, 8), 512, 0, stream>>>(xb, wt, bq, bk, Qp, Kp);
  qkv_gemm<<<dim3(64, 8), 256, 0, stream>>>(xb, wt, bq, bk, bv, Qp, Kp, vtp, 2048);
  qk_scores<<<dim3(136, 4), 256, 0, stream>>>(Qp, Kp, sc);
  softmax_row<<<8192, 256, 0, stream>>>(sc, pb);
  pv_gemm<<<dim3(8, 8, 4), 256, 0, stream>>>(pb, vtp, out);
}

// Round 13
// 150.636 us; speedup vs baseline: 1.0373x; 1.0373x over previous
//
#include <hip/hip_runtime.h>
#include <hip/hip_bf16.h>
#include <cstdint>

#define D_MODEL 1024
#define SEQ     2048
#define SCALE   0.125f
#define P_ELEMS 2228224   // per-batch packed triangular elems: 16384*136

typedef __attribute__((ext_vector_type(8))) _Float16 f16x8;
typedef __attribute__((ext_vector_type(8))) unsigned short u16x8;
typedef __attribute__((ext_vector_type(4))) float f32x4;

__device__ __forceinline__ unsigned short f2h(float f) {
  _Float16 h = (_Float16)f;
  return __builtin_bit_cast(unsigned short, h);
}
__device__ __forceinline__ float h2f(unsigned short u) {
  return (float)__builtin_bit_cast(_Float16, u);
}

__device__ __forceinline__ void gll16(const void* g, void* lds_p) {
  __builtin_amdgcn_global_load_lds(
      (const __attribute__((address_space(1))) unsigned int*)(uintptr_t)g,
      (__attribute__((address_space(3))) unsigned int*)(unsigned int)(uintptr_t)lds_p,
      16, 0, 0);
}

#define WAITV8 asm volatile("s_waitcnt vmcnt(8)" ::: "memory")
#define WAITV0 asm volatile("s_waitcnt vmcnt(0)" ::: "memory")
#define WAITL8 asm volatile("s_waitcnt lgkmcnt(8)" ::: "memory")
#define WAITL0 asm volatile("s_waitcnt lgkmcnt(0)" ::: "memory")
#define SCHEDB __builtin_amdgcn_sched_barrier(0)
#define BAR    __builtin_amdgcn_s_barrier()
#define PRIO1  __builtin_amdgcn_s_setprio(1)
#define PRIO0  __builtin_amdgcn_s_setprio(0)
#define MFMA16(a, b, c) __builtin_amdgcn_mfma_f32_16x16x32_f16(a, b, c, 0, 0, 0)

// ============ 128-tile pipeline (4 waves) ============
__device__ __forceinline__ void stage_tile(const unsigned short* gA, const unsigned short* gB,
                                           size_t sA, size_t sB,
                                           int k0, unsigned short* buf, int w, int lane) {
  int rl = lane >> 3;
  int sg = ((lane & 7) ^ rl) << 3;
#pragma unroll
  for (int j = 0; j < 4; j++) {
    int c = w * 4 + j;
    int row = c * 8 + rl;
    gll16(gA + (size_t)row * sA + k0 + sg, buf + c * 512);
    gll16(gB + (size_t)row * sB + k0 + sg, buf + 8192 + c * 512);
  }
}

__device__ __forceinline__ void gemm_core(const unsigned short* gA, const unsigned short* gB,
                                          size_t sA, size_t sB,
                                          unsigned short* lds0, unsigned short* lds1, int nt,
                                          int w, int lane, int wr, int wc, int l15, int l4,
                                          f32x4 acc[4][4]) {
  stage_tile(gA, gB, sA, sB, 0, lds0, w, lane);
  stage_tile(gA, gB, sA, sB, 64, lds1, w, lane);
  WAITV8; SCHEDB; BAR;
  for (int t = 0; t < nt; t++) {
    const unsigned short* buf = (t & 1) ? lds1 : lds0;
    const unsigned short* bA = buf;
    const unsigned short* bB = buf + 8192;
    f16x8 a0[4], b0[4], a1[4], b1[4];
#pragma unroll
    for (int m = 0; m < 4; m++) {
      int row = wr * 64 + m * 16 + l15, rs = row & 7;
      a0[m] = *(const f16x8*)(bA + row * 64 + ((l4 ^ rs) << 3));
    }
#pragma unroll
    for (int n = 0; n < 4; n++) {
      int row = wc * 64 + n * 16 + l15, rs = row & 7;
      b0[n] = *(const f16x8*)(bB + row * 64 + ((l4 ^ rs) << 3));
    }
#pragma unroll
    for (int m = 0; m < 4; m++) {
      int row = wr * 64 + m * 16 + l15, rs = row & 7;
      a1[m] = *(const f16x8*)(bA + row * 64 + (((4 + l4) ^ rs) << 3));
    }
#pragma unroll
    for (int n = 0; n < 4; n++) {
      int row = wc * 64 + n * 16 + l15, rs = row & 7;
      b1[n] = *(const f16x8*)(bB + row * 64 + (((4 + l4) ^ rs) << 3));
    }
    WAITL8; SCHEDB;
    PRIO1;
#pragma unroll
    for (int m = 0; m < 4; m++)
#pragma unroll
      for (int n = 0; n < 4; n++)
        acc[m][n] = MFMA16(a0[m], b0[n], acc[m][n]);
    PRIO0;
    WAITL0; SCHEDB; BAR;
    if (t + 2 < nt) stage_tile(gA, gB, sA, sB, (t + 2) * 64,
                               (unsigned short*)buf, w, lane);
    PRIO1;
#pragma unroll
    for (int m = 0; m < 4; m++)
#pragma unroll
      for (int n = 0; n < 4; n++)
        acc[m][n] = MFMA16(a1[m], b1[n], acc[m][n]);
    PRIO0;
    if (t + 2 < nt) { WAITV8; } else { WAITV0; }
    SCHEDB; BAR;
  }
}

// ---- kernel 1: fused converts. blocks 0..4095: x f32->f16; 4096..7167: W transpose ----
__global__ __launch_bounds__(256) void cvt_fused(const float* __restrict__ x,
                                                 const float* __restrict__ W0,
                                                 const float* __restrict__ W1,
                                                 const float* __restrict__ W2,
                                                 unsigned short* __restrict__ xb,
                                                 unsigned short* __restrict__ wt) {
  __shared__ float t[32][33];
  int bid = blockIdx.x;
  int tid = threadIdx.x;
  if (bid < 4096) {
    int i = bid * 256 + tid;
    const float4* p = (const float4*)x + (size_t)i * 2;
    float4 a = p[0], b = p[1];
    u16x8 r;
    r[0] = f2h(a.x); r[1] = f2h(a.y); r[2] = f2h(a.z); r[3] = f2h(a.w);
    r[4] = f2h(b.x); r[5] = f2h(b.y); r[6] = f2h(b.z); r[7] = f2h(b.w);
    *((u16x8*)xb + i) = r;
  } else {
    int id = bid - 4096;              // 0..3071
    int z = id >> 10, rem = id & 1023;
    int bx = rem & 31, by = rem >> 5;
    const float* W = (z == 0) ? W0 : (z == 1 ? W1 : W2);
    unsigned short* o = wt + (size_t)z * 1048576;
    int c0 = bx * 32, r0 = by * 32;
    int tx = tid & 31, ty = tid >> 5;
    for (int i = 0; i < 4; i++)
      t[ty + 8 * i][tx] = W[(size_t)(r0 + ty + 8 * i) * 1024 + c0 + tx];
    __syncthreads();
    for (int i = 0; i < 4; i++)
      o[(size_t)(c0 + ty + 8 * i) * 1024 + r0 + tx] = f2h(t[tx][ty + 8 * i]);
  }
}

// ---- kernel 2: fused QKV GEMM (r11 structure, natural mapping, 1536 blocks) ----
__global__ __launch_bounds__(256) void qkv_gemm(const unsigned short* __restrict__ xb,
                                                const unsigned short* __restrict__ wt,
                                                const float* __restrict__ b0,
                                                const float* __restrict__ b1,
                                                const float* __restrict__ b2,
                                                unsigned short* __restrict__ Qp,
                                                unsigned short* __restrict__ Kp,
                                                unsigned short* __restrict__ vtp) {
  __shared__ unsigned short lds[2][16384];   // [buf][A 8192 | B 8192]
  int m0 = blockIdx.x * 128;
  int n0 = blockIdx.y * 128;
  int z = n0 >> 10, nz = n0 & 1023;
  const unsigned short* gA = xb + (size_t)m0 * 1024;
  const unsigned short* gB = wt + (size_t)z * 1048576 + (size_t)nz * 1024;
  const float* bias = (z == 0) ? b0 : (z == 1 ? b1 : b2);
  int tid = threadIdx.x, lane = tid & 63, w = tid >> 6;
  int wr = w >> 1, wc = w & 1, l15 = lane & 15, l4 = lane >> 4;
  f32x4 acc[4][4] = {};
  gemm_core(gA, gB, 1024, 1024, &lds[0][0], &lds[1][0], 16, w, lane, wr, wc, l15, l4, acc);

  if (z < 2) {
    unsigned short* O = (z == 0) ? Qp : Kp;
#pragma unroll
    for (int m = 0; m < 4; m++)
#pragma unroll
      for (int n = 0; n < 4; n++) {
        int cl = wc * 64 + n * 16 + l15;
        float bv = bias[nz + cl];
#pragma unroll
        for (int r = 0; r < 4; r++) {
          int row = m0 + wr * 64 + m * 16 + l4 * 4 + r;
          O[(size_t)row * 1024 + nz + cl] = f2h(acc[m][n][r] + bv);
        }
      }
  } else {
    // V: transpose 128x128 tile in LDS, then coalesced store to vtp[b][d][s]
    unsigned short* T = &lds[0][0];          // 128 x 136 f16
#pragma unroll
    for (int m = 0; m < 4; m++)
#pragma unroll
      for (int n = 0; n < 4; n++) {
        int cl = wc * 64 + n * 16 + l15;     // d-local
        float bv = bias[nz + cl];
#pragma unroll
        for (int r = 0; r < 4; r++) {
          int rl = wr * 64 + m * 16 + l4 * 4 + r;   // s-local
          T[cl * 136 + rl] = f2h(acc[m][n][r] + bv);
        }
      }
    __syncthreads();
    int bidx = m0 >> 11, s0 = m0 & 2047;
#pragma unroll
    for (int i = 0; i < 8; i++) {
      int d = w * 32 + i * 4 + (lane >> 4);
      int ch = lane & 15;
      u16x8 v = *(const u16x8*)(T + d * 136 + ch * 8);
      *(u16x8*)(vtp + ((size_t)bidx * 1024 + nz + d) * 2048 + s0 + ch * 8) = v;
    }
  }
}

// ---- kernel 3: scores — 512 blocks; 32 "double" blocks (2 tiles) dispatched first ----
__global__ __launch_bounds__(256) void qk_scores(const unsigned short* __restrict__ Q,
                                                 const unsigned short* __restrict__ Kb,
                                                 unsigned short* __restrict__ sc) {
  __shared__ unsigned short lds[2][16384];
  int blk = blockIdx.x;
  int t0, ntile;
  if (blk < 32) { t0 = 480 + blk; ntile = 2; }     // tiles 480+blk, 512+blk
  else          { t0 = blk - 32;  ntile = 1; }     // tiles 0..479
  int tid = threadIdx.x, lane = tid & 63, w = tid >> 6;
  int wr = w >> 1, wc = w & 1, l15 = lane & 15, l4 = lane >> 4;
  for (int u = 0; u < ntile; u++) {
    int ti = t0 + u * 32;
    int b = ti / 136, i = ti % 136;
    int qt = (int)((sqrtf(8.f * i + 1.f) - 1.f) * 0.5f);
    while ((qt + 1) * (qt + 2) / 2 <= i) qt++;
    while (qt * (qt + 1) / 2 > i) qt--;
    int kt = i - qt * (qt + 1) / 2;
    int Wspan = (qt + 1) << 7;
    const unsigned short* gA = Q  + ((size_t)b * 2048 + qt * 128) * 1024;
    const unsigned short* gB = Kb + ((size_t)b * 2048 + kt * 128) * 1024;
    unsigned short* outp = sc + (size_t)b * P_ELEMS + (size_t)16384 * (qt * (qt + 1) / 2);
    f32x4 acc[4][4] = {};
    gemm_core(gA, gB, 1024, 1024, &lds[0][0], &lds[1][0], 16, w, lane, wr, wc, l15, l4, acc);
#pragma unroll
    for (int m = 0; m < 4; m++)
#pragma unroll
      for (int n = 0; n < 4; n++) {
        int cl = wc * 64 + n * 16 + l15;
        int kv = kt * 128 + cl;
#pragma unroll
        for (int r = 0; r < 4; r++) {
          int rl = wr * 64 + m * 16 + l4 * 4 + r;
          int srow = qt * 128 + rl;
          float v = acc[m][n][r] * SCALE;
          if (kv > srow) v = -30000.f;
          outp[(size_t)rl * Wspan + kv] = f2h(v);
        }
      }
  }
}

// ---- kernel 4: row softmax over f16 scores, write f16 P ----
__global__ __launch_bounds__(256) void softmax_row(const unsigned short* __restrict__ sc,
                                                   unsigned short* __restrict__ pb) {
  __shared__ float redm[4];
  __shared__ float reds[4];
  int srow = blockIdx.x;
  int b = srow >> 11, sl = srow & 2047;
  int qt = sl >> 7;
  int Wspan = (qt + 1) << 7;
  size_t rb = (size_t)b * P_ELEMS + (size_t)16384 * (qt * (qt + 1) / 2) + (size_t)(sl & 127) * Wspan;
  const u16x8* src = (const u16x8*)(sc + rb);
  int nv = Wspan >> 3;
  int t = threadIdx.x, lane = t & 63, w = t >> 6;
  bool h0 = t < nv;
  float v[8];
  float mx = -1e30f;
  if (h0) {
    u16x8 raw = src[t];
#pragma unroll
    for (int j = 0; j < 8; j++) { v[j] = h2f(raw[j]); mx = fmaxf(mx, v[j]); }
  }
  for (int off = 1; off < 64; off <<= 1) mx = fmaxf(mx, __shfl_xor(mx, off, 64));
  if (lane == 0) redm[w] = mx;
  __syncthreads();
  mx = fmaxf(fmaxf(redm[0], redm[1]), fmaxf(redm[2], redm[3]));
  float s = 0.f;
  if (h0) {
#pragma unroll
    for (int j = 0; j < 8; j++) { v[j] = __expf(v[j] - mx); s += v[j]; }
  }
  for (int off = 1; off < 64; off <<= 1) s += __shfl_xor(s, off, 64);
  if (lane == 0) reds[w] = s;
  __syncthreads();
  s = reds[0] + reds[1] + reds[2] + reds[3];
  float inv = 1.f / s;
  if (h0) {
    u16x8 o;
#pragma unroll
    for (int j = 0; j < 8; j++) o[j] = f2h(v[j] * inv);
    *((u16x8*)(pb + rb) + t) = o;
  }
}

// ---- kernel 5: O = P Vt — 512 blocks, z-conjugate qt balance ----
// Co-resident pair (c, c+256) differs only in bz by 2 -> qt + qt' = 15 -> 34 iters/CU.
__global__ __launch_bounds__(256) void pv_gemm(const unsigned short* __restrict__ pb,
                                               const unsigned short* __restrict__ vtp,
                                               float* __restrict__ outp) {
  __shared__ unsigned short lds[2][16384];
  int bx = blockIdx.x;       // 0..15
  int n0 = blockIdx.y * 128;
  int bz = blockIdx.z;       // 0..3 (batch)
  int qt = (bz & 2) ? (15 - bx) : bx;
  int b = bz;
  int tid = threadIdx.x, lane = tid & 63, w = tid >> 6;
  int wr = w >> 1, wc = w & 1, l15 = lane & 15, l4 = lane >> 4;
  const unsigned short* gB = vtp + (size_t)b * 1024 * 2048 + (size_t)n0 * 2048;
  int Wspan = (qt + 1) << 7;
  const unsigned short* gA = pb + (size_t)b * P_ELEMS + (size_t)16384 * (qt * (qt + 1) / 2);
  float* O = outp + ((size_t)b * 2048 + qt * 128) * 1024;
  f32x4 acc[4][4] = {};
  gemm_core(gA, gB, Wspan, 2048, &lds[0][0], &lds[1][0], 2 * (qt + 1),
            w, lane, wr, wc, l15, l4, acc);
#pragma unroll
  for (int m = 0; m < 4; m++)
#pragma unroll
    for (int n = 0; n < 4; n++) {
      int cl = n0 + wc * 64 + n * 16 + l15;
#pragma unroll
      for (int r = 0; r < 4; r++) {
        int rl = wr * 64 + m * 16 + l4 * 4 + r;
        O[(size_t)rl * 1024 + cl] = acc[m][n][r];
      }
    }
}

extern "C" void kernel_launch(void* const* d_in, const int* in_sizes, int n_in,
                              void* d_out, int out_size, void* d_ws, size_t ws_size,
                              hipStream_t stream) {
  const float* x  = (const float*)d_in[0];
  const float* Wq = (const float*)d_in[1];
  const float* bq = (const float*)d_in[2];
  const float* Wk = (const float*)d_in[3];
  const float* bk = (const float*)d_in[4];
  const float* Wv = (const float*)d_in[5];
  const float* bv = (const float*)d_in[6];
  float* out = (float*)d_out;

  unsigned short* ws  = (unsigned short*)d_ws;
  unsigned short* wt  = ws;                          // 3,145,728 ushorts
  unsigned short* Qp  = ws + 3145728;                // 8,388,608
  unsigned short* Kp  = ws + 11534336;               // 8,388,608
  unsigned short* vtp = ws + 19922944;               // 8,388,608 (V^T [b][d][s])
  unsigned short* sc  = ws + 28311552;               // 4*P_ELEMS f16 scores
  unsigned short* pb  = ws + 37224448;               // 4*P_ELEMS f16 P
  unsigned short* xb  = (unsigned short*)d_out;      // x f16 scratch (overwritten by pv)

  cvt_fused<<<7168, 256, 0, stream>>>(x, Wq, Wk, Wv, xb, wt);
  qkv_gemm<<<dim3(64, 24), 256, 0, stream>>>(xb, wt, bq, bk, bv, Qp, Kp, vtp);
  qk_scores<<<512, 256, 0, stream>>>(Qp, Kp, sc);
  softmax_row<<<8192, 256, 0, stream>>>(sc, pb);
  pv_gemm<<<dim3(16, 8, 4), 256, 0, stream>>>(pb, vtp, out);
}

// Round 14
// 149.743 us; speedup vs baseline: 1.0435x; 1.0060x over previous
//
#include <hip/hip_runtime.h>
#include <hip/hip_bf16.h>
#include <cstdint>

#define D_MODEL 1024
#define SEQ     2048
#define SCALE   0.125f
#define P_ELEMS 2228224   // per-batch packed triangular elems: 16384*136

typedef __attribute__((ext_vector_type(8))) _Float16 f16x8;
typedef __attribute__((ext_vector_type(8))) unsigned short u16x8;
typedef __attribute__((ext_vector_type(4))) float f32x4;

__device__ __forceinline__ unsigned short f2h(float f) {
  _Float16 h = (_Float16)f;
  return __builtin_bit_cast(unsigned short, h);
}
__device__ __forceinline__ float h2f(unsigned short u) {
  return (float)__builtin_bit_cast(_Float16, u);
}

__device__ __forceinline__ void gll16(const void* g, void* lds_p) {
  __builtin_amdgcn_global_load_lds(
      (const __attribute__((address_space(1))) unsigned int*)(uintptr_t)g,
      (__attribute__((address_space(3))) unsigned int*)(unsigned int)(uintptr_t)lds_p,
      16, 0, 0);
}

#define WAITV8 asm volatile("s_waitcnt vmcnt(8)" ::: "memory")
#define WAITV0 asm volatile("s_waitcnt vmcnt(0)" ::: "memory")
#define WAITL8 asm volatile("s_waitcnt lgkmcnt(8)" ::: "memory")
#define WAITL0 asm volatile("s_waitcnt lgkmcnt(0)" ::: "memory")
#define SCHEDB __builtin_amdgcn_sched_barrier(0)
#define BAR    __builtin_amdgcn_s_barrier()
#define PRIO1  __builtin_amdgcn_s_setprio(1)
#define PRIO0  __builtin_amdgcn_s_setprio(0)
#define MFMA16(a, b, c) __builtin_amdgcn_mfma_f32_16x16x32_f16(a, b, c, 0, 0, 0)

// ============ 128-tile pipeline (4 waves) ============
__device__ __forceinline__ void stage_tile(const unsigned short* gA, const unsigned short* gB,
                                           size_t sA, size_t sB,
                                           int k0, unsigned short* buf, int w, int lane) {
  int rl = lane >> 3;
  int sg = ((lane & 7) ^ rl) << 3;
#pragma unroll
  for (int j = 0; j < 4; j++) {
    int c = w * 4 + j;
    int row = c * 8 + rl;
    gll16(gA + (size_t)row * sA + k0 + sg, buf + c * 512);
    gll16(gB + (size_t)row * sB + k0 + sg, buf + 8192 + c * 512);
  }
}

__device__ __forceinline__ void gemm_core(const unsigned short* gA, const unsigned short* gB,
                                          size_t sA, size_t sB,
                                          unsigned short* lds0, unsigned short* lds1, int nt,
                                          int w, int lane, int wr, int wc, int l15, int l4,
                                          f32x4 acc[4][4]) {
  stage_tile(gA, gB, sA, sB, 0, lds0, w, lane);
  stage_tile(gA, gB, sA, sB, 64, lds1, w, lane);
  WAITV8; SCHEDB; BAR;
  for (int t = 0; t < nt; t++) {
    const unsigned short* buf = (t & 1) ? lds1 : lds0;
    const unsigned short* bA = buf;
    const unsigned short* bB = buf + 8192;
    f16x8 a0[4], b0[4], a1[4], b1[4];
#pragma unroll
    for (int m = 0; m < 4; m++) {
      int row = wr * 64 + m * 16 + l15, rs = row & 7;
      a0[m] = *(const f16x8*)(bA + row * 64 + ((l4 ^ rs) << 3));
    }
#pragma unroll
    for (int n = 0; n < 4; n++) {
      int row = wc * 64 + n * 16 + l15, rs = row & 7;
      b0[n] = *(const f16x8*)(bB + row * 64 + ((l4 ^ rs) << 3));
    }
#pragma unroll
    for (int m = 0; m < 4; m++) {
      int row = wr * 64 + m * 16 + l15, rs = row & 7;
      a1[m] = *(const f16x8*)(bA + row * 64 + (((4 + l4) ^ rs) << 3));
    }
#pragma unroll
    for (int n = 0; n < 4; n++) {
      int row = wc * 64 + n * 16 + l15, rs = row & 7;
      b1[n] = *(const f16x8*)(bB + row * 64 + (((4 + l4) ^ rs) << 3));
    }
    WAITL8; SCHEDB;
    PRIO1;
#pragma unroll
    for (int m = 0; m < 4; m++)
#pragma unroll
      for (int n = 0; n < 4; n++)
        acc[m][n] = MFMA16(a0[m], b0[n], acc[m][n]);
    PRIO0;
    WAITL0; SCHEDB; BAR;
    if (t + 2 < nt) stage_tile(gA, gB, sA, sB, (t + 2) * 64,
                               (unsigned short*)buf, w, lane);
    PRIO1;
#pragma unroll
    for (int m = 0; m < 4; m++)
#pragma unroll
      for (int n = 0; n < 4; n++)
        acc[m][n] = MFMA16(a1[m], b1[n], acc[m][n]);
    PRIO0;
    if (t + 2 < nt) { WAITV8; } else { WAITV0; }
    SCHEDB; BAR;
  }
}

// ---- kernel 1: fused converts. blocks 0..4095: x f32->f16; 4096..7167: W transpose ----
__global__ __launch_bounds__(256) void cvt_fused(const float* __restrict__ x,
                                                 const float* __restrict__ W0,
                                                 const float* __restrict__ W1,
                                                 const float* __restrict__ W2,
                                                 unsigned short* __restrict__ xb,
                                                 unsigned short* __restrict__ wt) {
  __shared__ float t[32][33];
  int bid = blockIdx.x;
  int tid = threadIdx.x;
  if (bid < 4096) {
    int i = bid * 256 + tid;
    const float4* p = (const float4*)x + (size_t)i * 2;
    float4 a = p[0], b = p[1];
    u16x8 r;
    r[0] = f2h(a.x); r[1] = f2h(a.y); r[2] = f2h(a.z); r[3] = f2h(a.w);
    r[4] = f2h(b.x); r[5] = f2h(b.y); r[6] = f2h(b.z); r[7] = f2h(b.w);
    *((u16x8*)xb + i) = r;
  } else {
    int id = bid - 4096;              // 0..3071
    int z = id >> 10, rem = id & 1023;
    int bx = rem & 31, by = rem >> 5;
    const float* W = (z == 0) ? W0 : (z == 1 ? W1 : W2);
    unsigned short* o = wt + (size_t)z * 1048576;
    int c0 = bx * 32, r0 = by * 32;
    int tx = tid & 31, ty = tid >> 5;
    for (int i = 0; i < 4; i++)
      t[ty + 8 * i][tx] = W[(size_t)(r0 + ty + 8 * i) * 1024 + c0 + tx];
    __syncthreads();
    for (int i = 0; i < 4; i++)
      o[(size_t)(c0 + ty + 8 * i) * 1024 + r0 + tx] = f2h(t[tx][ty + 8 * i]);
  }
}

// ---- kernel 2: fused QKV GEMM; all outputs via coalesced LDS-bounce epilogue ----
__global__ __launch_bounds__(256) void qkv_gemm(const unsigned short* __restrict__ xb,
                                                const unsigned short* __restrict__ wt,
                                                const float* __restrict__ b0,
                                                const float* __restrict__ b1,
                                                const float* __restrict__ b2,
                                                unsigned short* __restrict__ Qp,
                                                unsigned short* __restrict__ Kp,
                                                unsigned short* __restrict__ vtp) {
  __shared__ unsigned short lds[2][16384];   // [buf][A 8192 | B 8192]
  int m0 = blockIdx.x * 128;
  int n0 = blockIdx.y * 128;
  int z = n0 >> 10, nz = n0 & 1023;
  const unsigned short* gA = xb + (size_t)m0 * 1024;
  const unsigned short* gB = wt + (size_t)z * 1048576 + (size_t)nz * 1024;
  const float* bias = (z == 0) ? b0 : (z == 1 ? b1 : b2);
  int tid = threadIdx.x, lane = tid & 63, w = tid >> 6;
  int wr = w >> 1, wc = w & 1, l15 = lane & 15, l4 = lane >> 4;
  f32x4 acc[4][4] = {};
  gemm_core(gA, gB, 1024, 1024, &lds[0][0], &lds[1][0], 16, w, lane, wr, wc, l15, l4, acc);

  unsigned short* T = &lds[0][0];            // 128 x 136 f16 bounce
  if (z < 2) {
    unsigned short* O = (z == 0) ? Qp : Kp;
#pragma unroll
    for (int m = 0; m < 4; m++)
#pragma unroll
      for (int n = 0; n < 4; n++) {
        int cl = wc * 64 + n * 16 + l15;
        float bv = bias[nz + cl];
#pragma unroll
        for (int r = 0; r < 4; r++) {
          int rl = wr * 64 + m * 16 + l4 * 4 + r;
          T[rl * 136 + cl] = f2h(acc[m][n][r] + bv);
        }
      }
    __syncthreads();
#pragma unroll
    for (int i = 0; i < 8; i++) {
      int idx = i * 256 + tid;               // 2048 chunks: 128 rows x 16
      int row = idx >> 4, ch = idx & 15;
      u16x8 v = *(const u16x8*)(T + row * 136 + ch * 8);
      *(u16x8*)(O + (size_t)(m0 + row) * 1024 + nz + ch * 8) = v;
    }
  } else {
    // V: transposed bounce -> vtp[b][d][s]
#pragma unroll
    for (int m = 0; m < 4; m++)
#pragma unroll
      for (int n = 0; n < 4; n++) {
        int cl = wc * 64 + n * 16 + l15;     // d-local
        float bv = bias[nz + cl];
#pragma unroll
        for (int r = 0; r < 4; r++) {
          int rl = wr * 64 + m * 16 + l4 * 4 + r;   // s-local
          T[cl * 136 + rl] = f2h(acc[m][n][r] + bv);
        }
      }
    __syncthreads();
    int bidx = m0 >> 11, s0 = m0 & 2047;
#pragma unroll
    for (int i = 0; i < 8; i++) {
      int d = w * 32 + i * 4 + (lane >> 4);
      int ch = lane & 15;
      u16x8 v = *(const u16x8*)(T + d * 136 + ch * 8);
      *(u16x8*)(vtp + ((size_t)bidx * 1024 + nz + d) * 2048 + s0 + ch * 8) = v;
    }
  }
}

// ---- kernel 3: scores — 512 blocks; 32 "double" blocks first; LDS-bounce epilogue ----
__global__ __launch_bounds__(256) void qk_scores(const unsigned short* __restrict__ Q,
                                                 const unsigned short* __restrict__ Kb,
                                                 unsigned short* __restrict__ sc) {
  __shared__ unsigned short lds[2][16384];
  int blk = blockIdx.x;
  int t0, ntile;
  if (blk < 32) { t0 = 480 + blk; ntile = 2; }
  else          { t0 = blk - 32;  ntile = 1; }
  int tid = threadIdx.x, lane = tid & 63, w = tid >> 6;
  int wr = w >> 1, wc = w & 1, l15 = lane & 15, l4 = lane >> 4;
  for (int u = 0; u < ntile; u++) {
    int ti = t0 + u * 32;
    int b = ti / 136, i = ti % 136;
    int qt = (int)((sqrtf(8.f * i + 1.f) - 1.f) * 0.5f);
    while ((qt + 1) * (qt + 2) / 2 <= i) qt++;
    while (qt * (qt + 1) / 2 > i) qt--;
    int kt = i - qt * (qt + 1) / 2;
    int Wspan = (qt + 1) << 7;
    const unsigned short* gA = Q  + ((size_t)b * 2048 + qt * 128) * 1024;
    const unsigned short* gB = Kb + ((size_t)b * 2048 + kt * 128) * 1024;
    unsigned short* outp = sc + (size_t)b * P_ELEMS + (size_t)16384 * (qt * (qt + 1) / 2);
    f32x4 acc[4][4] = {};
    gemm_core(gA, gB, 1024, 1024, &lds[0][0], &lds[1][0], 16, w, lane, wr, wc, l15, l4, acc);
    unsigned short* T = &lds[0][0];          // 128 x 136 bounce
#pragma unroll
    for (int m = 0; m < 4; m++)
#pragma unroll
      for (int n = 0; n < 4; n++) {
        int cl = wc * 64 + n * 16 + l15;
        int kv = kt * 128 + cl;
#pragma unroll
        for (int r = 0; r < 4; r++) {
          int rl = wr * 64 + m * 16 + l4 * 4 + r;
          int srow = qt * 128 + rl;
          float v = acc[m][n][r] * SCALE;
          if (kv > srow) v = -30000.f;
          T[rl * 136 + cl] = f2h(v);
        }
      }
    __syncthreads();
#pragma unroll
    for (int i2 = 0; i2 < 8; i2++) {
      int idx = i2 * 256 + tid;
      int row = idx >> 4, ch = idx & 15;
      u16x8 v = *(const u16x8*)(T + row * 136 + ch * 8);
      *(u16x8*)(outp + (size_t)row * Wspan + kt * 128 + ch * 8) = v;
    }
    __syncthreads();                          // T dead before next tile's staging
  }
}

// ---- kernel 4: per-wave row softmax (4 same-width rows per block, no barriers) ----
__global__ __launch_bounds__(256) void softmax_row(const unsigned short* __restrict__ sc,
                                                   unsigned short* __restrict__ pb) {
  int base = blockIdx.x * 4;
  int b = base >> 11, sl0 = base & 2047;
  int w = threadIdx.x >> 6, lane = threadIdx.x & 63;
  int sl = sl0 + w;
  int qt = sl >> 7;
  int Wspan = (qt + 1) << 7;
  size_t rb = (size_t)b * P_ELEMS + (size_t)16384 * (qt * (qt + 1) / 2) + (size_t)(sl & 127) * Wspan;
  const u16x8* src = (const u16x8*)(sc + rb);
  int nc = Wspan >> 3;                       // 16..256 chunks
  bool h0 = lane < nc, h1 = lane + 64 < nc, h2 = lane + 128 < nc, h3 = lane + 192 < nc;
  float v0[8], v1[8], v2[8], v3[8];
  float mx = -1e30f;
  if (h0) { u16x8 r = src[lane];
#pragma unroll
    for (int j = 0; j < 8; j++) { v0[j] = h2f(r[j]); mx = fmaxf(mx, v0[j]); } }
  if (h1) { u16x8 r = src[lane + 64];
#pragma unroll
    for (int j = 0; j < 8; j++) { v1[j] = h2f(r[j]); mx = fmaxf(mx, v1[j]); } }
  if (h2) { u16x8 r = src[lane + 128];
#pragma unroll
    for (int j = 0; j < 8; j++) { v2[j] = h2f(r[j]); mx = fmaxf(mx, v2[j]); } }
  if (h3) { u16x8 r = src[lane + 192];
#pragma unroll
    for (int j = 0; j < 8; j++) { v3[j] = h2f(r[j]); mx = fmaxf(mx, v3[j]); } }
  for (int off = 1; off < 64; off <<= 1) mx = fmaxf(mx, __shfl_xor(mx, off, 64));
  float s = 0.f;
  if (h0) {
#pragma unroll
    for (int j = 0; j < 8; j++) { v0[j] = __expf(v0[j] - mx); s += v0[j]; } }
  if (h1) {
#pragma unroll
    for (int j = 0; j < 8; j++) { v1[j] = __expf(v1[j] - mx); s += v1[j]; } }
  if (h2) {
#pragma unroll
    for (int j = 0; j < 8; j++) { v2[j] = __expf(v2[j] - mx); s += v2[j]; } }
  if (h3) {
#pragma unroll
    for (int j = 0; j < 8; j++) { v3[j] = __expf(v3[j] - mx); s += v3[j]; } }
  for (int off = 1; off < 64; off <<= 1) s += __shfl_xor(s, off, 64);
  float inv = 1.f / s;
  u16x8* dst = (u16x8*)(pb + rb);
  if (h0) { u16x8 o;
#pragma unroll
    for (int j = 0; j < 8; j++) o[j] = f2h(v0[j] * inv);
    dst[lane] = o; }
  if (h1) { u16x8 o;
#pragma unroll
    for (int j = 0; j < 8; j++) o[j] = f2h(v1[j] * inv);
    dst[lane + 64] = o; }
  if (h2) { u16x8 o;
#pragma unroll
    for (int j = 0; j < 8; j++) o[j] = f2h(v2[j] * inv);
    dst[lane + 128] = o; }
  if (h3) { u16x8 o;
#pragma unroll
    for (int j = 0; j < 8; j++) o[j] = f2h(v3[j] * inv);
    dst[lane + 192] = o; }
}

// ---- kernel 5: O = P Vt — 512 blocks, z-conjugate balance, f32 LDS-bounce epilogue ----
__global__ __launch_bounds__(256) void pv_gemm(const unsigned short* __restrict__ pb,
                                               const unsigned short* __restrict__ vtp,
                                               float* __restrict__ outp) {
  __shared__ unsigned short lds[2][16384];
  int bx = blockIdx.x;       // 0..15
  int n0 = blockIdx.y * 128;
  int bz = blockIdx.z;       // 0..3
  int qt = (bz & 2) ? (15 - bx) : bx;
  int b = bz;
  int tid = threadIdx.x, lane = tid & 63, w = tid >> 6;
  int wr = w >> 1, wc = w & 1, l15 = lane & 15, l4 = lane >> 4;
  const unsigned short* gB = vtp + (size_t)b * 1024 * 2048 + (size_t)n0 * 2048;
  int Wspan = (qt + 1) << 7;
  const unsigned short* gA = pb + (size_t)b * P_ELEMS + (size_t)16384 * (qt * (qt + 1) / 2);
  float* O = outp + ((size_t)b * 2048 + qt * 128) * 1024;
  f32x4 acc[4][4] = {};
  gemm_core(gA, gB, Wspan, 2048, &lds[0][0], &lds[1][0], 2 * (qt + 1),
            w, lane, wr, wc, l15, l4, acc);
  // f32 bounce: T[128][128] (exactly 64 KB), float4-chunk swizzle cc^(row&7)
  float* Tf = (float*)&lds[0][0];
#pragma unroll
  for (int m = 0; m < 4; m++)
#pragma unroll
    for (int n = 0; n < 4; n++) {
      int cl = wc * 64 + n * 16 + l15;       // local col
#pragma unroll
      for (int r = 0; r < 4; r++) {
        int rl = wr * 64 + m * 16 + l4 * 4 + r;
        int cc = cl >> 2;
        int sw = (((cc ^ (rl & 7)) << 2) | (cl & 3));
        Tf[rl * 128 + sw] = acc[m][n][r];
      }
    }
  __syncthreads();
#pragma unroll
  for (int i = 0; i < 16; i++) {
    int idx = i * 256 + tid;                 // 4096 float4-chunks: 128 rows x 32
    int row = idx >> 5, ch = idx & 31;
    float4 val = *(const float4*)&Tf[row * 128 + ((ch ^ (row & 7)) << 2)];
    *(float4*)&O[(size_t)row * 1024 + n0 + ch * 4] = val;
  }
}

extern "C" void kernel_launch(void* const* d_in, const int* in_sizes, int n_in,
                              void* d_out, int out_size, void* d_ws, size_t ws_size,
                              hipStream_t stream) {
  const float* x  = (const float*)d_in[0];
  const float* Wq = (const float*)d_in[1];
  const float* bq = (const float*)d_in[2];
  const float* Wk = (const float*)d_in[3];
  const float* bk = (const float*)d_in[4];
  const float* Wv = (const float*)d_in[5];
  const float* bv = (const float*)d_in[6];
  float* out = (float*)d_out;

  unsigned short* ws  = (unsigned short*)d_ws;
  unsigned short* wt  = ws;                          // 3,145,728 ushorts
  unsigned short* Qp  = ws + 3145728;                // 8,388,608
  unsigned short* Kp  = ws + 11534336;               // 8,388,608
  unsigned short* vtp = ws + 19922944;               // 8,388,608 (V^T [b][d][s])
  unsigned short* sc  = ws + 28311552;               // 4*P_ELEMS f16 scores
  unsigned short* pb  = ws + 37224448;               // 4*P_ELEMS f16 P
  unsigned short* xb  = (unsigned short*)d_out;      // x f16 scratch (overwritten by pv)

  cvt_fused<<<7168, 256, 0, stream>>>(x, Wq, Wk, Wv, xb, wt);
  qkv_gemm<<<dim3(64, 24), 256, 0, stream>>>(xb, wt, bq, bk, bv, Qp, Kp, vtp);
  qk_scores<<<512, 256, 0, stream>>>(Qp, Kp, sc);
  softmax_row<<<2048, 256, 0, stream>>>(sc, pb);
  pv_gemm<<<dim3(16, 8, 4), 256, 0, stream>>>(pb, vtp, out);
}